// Round 4
// baseline (320.784 us; speedup 1.0000x reference)
//
#include <hip/hip_runtime.h>
#include <math.h>

#define BB 4
#define SS 8192
#define HH 16
#define DD 64
#define ROT 32
#define NG (BB * SS * HH)  // 524288 token-head rows
#define RPB 128            // rows per tile
#define LSTR 65            // LDS row stride in floats (pad +1 -> rotated banks)
#define TPB 512            // threads per block (8 waves)
#define NBLK 1024          // persistent blocks: exactly 4 per CU
#define TILES (NG / (RPB * NBLK))  // 4 tiles per block

typedef float f32x4 __attribute__((ext_vector_type(4)));  // native vec for NT store

// ---------------------------------------------------------------------------
// Merged setup: G_comb = I @ G_0 @ ... @ G_31 built in LDS (threads 0..63,
// column-op per row, no syncs needed among them), then M = G @ matrix.
// i==j edge: .at chain leaves G[i,i]=sin -> column i scaled by sin.
// ---------------------------------------------------------------------------
__global__ void setup_GM(const float* __restrict__ thetas,
                         const float* __restrict__ tscale,
                         const int* __restrict__ pairs,
                         const float* __restrict__ matrix,
                         float* __restrict__ M) {
  __shared__ float Gs[DD][DD];
  const int t = threadIdx.x;
  if (t < DD) {
    for (int c = 0; c < DD; ++c) Gs[t][c] = (t == c) ? 1.0f : 0.0f;
    const float ts = tscale[0];
    for (int r = 0; r < ROT; ++r) {
      const int i = pairs[2 * r], j = pairs[2 * r + 1];
      const float th = thetas[r] * ts;
      const float cc = cosf(th), sn = sinf(th);
      if (i == j) {
        Gs[t][i] *= sn;
      } else {
        const float a = Gs[t][i], b = Gs[t][j];
        Gs[t][i] = a * cc + b * sn;
        Gs[t][j] = b * cc - a * sn;
      }
    }
  }
  __syncthreads();
  const int e = blockIdx.x * 256 + t;
  const int row = e >> 6, col = e & 63;  // row wave-uniform -> LDS broadcast
  float a0 = 0.f, a1 = 0.f, a2 = 0.f, a3 = 0.f;
  for (int k = 0; k < DD; k += 4) {
    a0 = fmaf(Gs[row][k], matrix[k * DD + col], a0);
    a1 = fmaf(Gs[row][k + 1], matrix[(k + 1) * DD + col], a1);
    a2 = fmaf(Gs[row][k + 2], matrix[(k + 2) * DD + col], a2);
    a3 = fmaf(Gs[row][k + 3], matrix[(k + 3) * DD + col], a3);
  }
  M[e] = (a0 + a1) + (a2 + a3);
}

// cos/sin table PRESCALED by 32 (the sqrt(dims) factor fused here).
// tab[s*64 + d] = 32*cos(s*invf[d]); tab[s*64 + 32 + d] = 32*sin(...)
__global__ void setup_table(const float* __restrict__ invf,
                            float* __restrict__ tab) {
  const int idx = blockIdx.x * 256 + threadIdx.x;
  if (idx >= SS * 32) return;
  const int s = idx >> 5, d = idx & 31;
  const float ang = (float)s * invf[d];
  tab[s * 64 + d] = 32.0f * cosf(ang);
  tab[s * 64 + 32 + d] = 32.0f * sinf(ang);
}

// ---------------------------------------------------------------------------
// Main kernel: single-buffer LDS (33.3 KB -> 4 blocks/CU) + cross-tile
// register prefetch. Per tile:
//   A: load tab(t) then x(t+1) -> regs  (tab first: counted vmcnt keeps x
//      in flight through the epilogue; HBM latency hides under B)
//   B: matvec + RoPE epilogue from lds
//   B1: barrier; C: outputs -> lds; B2: barrier
//   D: coalesced NT store from lds; E: staged x(t+1) -> SAME per-thread lds
//      addrs (each float4 slot read in D and written in E by its owner
//      thread only -> no extra barrier); B4: barrier
// 3 barriers/tile (same as round 1) but loads overlap compute, fixing the
// convoy that capped HBM duty at ~40% (rounds 0-3: wall ~= bytes/2.6 TB/s).
// ---------------------------------------------------------------------------
__global__ __launch_bounds__(TPB, 8) void apply_rot(
    const float* __restrict__ x, const float* __restrict__ M,
    const float* __restrict__ tab, const float* __restrict__ invf,
    float* __restrict__ out) {
  __shared__ float lds[RPB * LSTR];  // 33280 B
  const int tid = threadIdx.x;
  const int r = tid & (RPB - 1);
  const int h = __builtin_amdgcn_readfirstlane(tid >> 7);  // 0..3, wave-uniform
  const float* __restrict__ Mh = M + h * 16;
  const size_t tile0 = (size_t)blockIdx.x * TILES;

  // Per-thread LDS float-offsets for the stage/store f-map.
  int fa[4];
#pragma unroll
  for (int i = 0; i < 4; ++i) {
    const int f = i * TPB + tid;
    fa[i] = (f >> 4) * LSTR + (f & 15) * 4;
  }

  // Prologue: stage x(tile0) -> lds.
  {
    const float4* __restrict__ xg = (const float4*)x + tile0 * (RPB * 16);
    const float4 s0 = xg[0 * TPB + tid], s1 = xg[1 * TPB + tid],
                 s2 = xg[2 * TPB + tid], s3 = xg[3 * TPB + tid];
    *(float4*)&lds[fa[0]] = s0;
    *(float4*)&lds[fa[1]] = s1;
    *(float4*)&lds[fa[2]] = s2;
    *(float4*)&lds[fa[3]] = s3;
  }
  __syncthreads();

  float4 st0, st1, st2, st3;
#pragma unroll 1
  for (int t = 0; t < TILES; ++t) {
    const size_t tile = tile0 + t;
    const int g = (int)(tile * RPB) + r;
    const int spos = (g >> 4) & (SS - 1);

    // A: tab loads for THIS tile first, then x prefetch for the next.
    float cz[8], sz[8];
    if (tab) {
      const float4* __restrict__ tc = (const float4*)(tab + spos * 64 + h * 8);
      const float4* __restrict__ tn =
          (const float4*)(tab + spos * 64 + 32 + h * 8);
      *(float4*)&cz[0] = tc[0];
      *(float4*)&cz[4] = tc[1];
      *(float4*)&sz[0] = tn[0];
      *(float4*)&sz[4] = tn[1];
    }
    if (t + 1 < TILES) {
      const float4* __restrict__ xg =
          (const float4*)x + (tile + 1) * (RPB * 16);
      st0 = xg[0 * TPB + tid];
      st1 = xg[1 * TPB + tid];
      st2 = xg[2 * TPB + tid];
      st3 = xg[3 * TPB + tid];
    }

    // B: thread (r,h) computes cols [16h, 16h+16) of row r.
    const float* __restrict__ xr = &lds[r * LSTR];
    float acc[16];
#pragma unroll
    for (int c = 0; c < 16; ++c) acc[c] = 0.0f;

#pragma unroll 4
    for (int k4 = 0; k4 < 16; ++k4) {
      const float4 xv = *(const float4*)&xr[k4 * 4];
      const float* __restrict__ m0 = Mh + k4 * 4 * DD;  // uniform -> s_load
#pragma unroll
      for (int c = 0; c < 16; ++c) acc[c] = fmaf(xv.x, m0[c], acc[c]);
#pragma unroll
      for (int c = 0; c < 16; ++c) acc[c] = fmaf(xv.y, m0[DD + c], acc[c]);
#pragma unroll
      for (int c = 0; c < 16; ++c) acc[c] = fmaf(xv.z, m0[2 * DD + c], acc[c]);
#pragma unroll
      for (int c = 0; c < 16; ++c) acc[c] = fmaf(xv.w, m0[3 * DD + c], acc[c]);
    }

    if (!tab) {
#pragma unroll
      for (int d = 0; d < 8; ++d) {
        const float ang = (float)spos * invf[h * 8 + d];
        cz[d] = 32.0f * cosf(ang);
        sz[d] = 32.0f * sinf(ang);
      }
    }

    // RoPE epilogue: pairs (2d,2d+1) -> out cols d (lo) and 32+d (hi), d=8h+d'.
    float4 lov[2], hiv[2];
#pragma unroll
    for (int q = 0; q < 2; ++q) {
#pragma unroll
      for (int d = 0; d < 4; ++d) {
        const int dd = 4 * q + d;
        const float e = acc[2 * dd], o = acc[2 * dd + 1];
        ((float*)&lov[q])[d] = e * cz[dd] - o * sz[dd];
        ((float*)&hiv[q])[d] = e * sz[dd] + o * cz[dd];
      }
    }

    // B1: all lds x-reads complete before overwrite with outputs.
    __syncthreads();

    // C: outputs -> lds (same padded layout).
    float* __restrict__ orow = &lds[r * LSTR];
    *(float4*)&orow[8 * h + 0] = lov[0];
    *(float4*)&orow[8 * h + 4] = lov[1];
    *(float4*)&orow[32 + 8 * h + 0] = hiv[0];
    *(float4*)&orow[32 + 8 * h + 4] = hiv[1];

    // B2: output tile fully assembled.
    __syncthreads();

    // D: coalesced NT stores; E: overwrite the SAME per-thread slots with the
    // prefetched next x tile (per-slot single owner -> no barrier between).
    float4* __restrict__ og = (float4*)out + tile * (RPB * 16);
#pragma unroll
    for (int i = 0; i < 4; ++i) {
      const float4 v = *(const float4*)&lds[fa[i]];
      __builtin_nontemporal_store(*(const f32x4*)&v,
                                  (f32x4*)&og[i * TPB + tid]);
    }
    if (t + 1 < TILES) {
      *(float4*)&lds[fa[0]] = st0;
      *(float4*)&lds[fa[1]] = st1;
      *(float4*)&lds[fa[2]] = st2;
      *(float4*)&lds[fa[3]] = st3;
    }
    // B4: staged x visible before next tile's compute reads.
    __syncthreads();
  }
}

// ---------------------------------------------------------------------------
extern "C" void kernel_launch(void* const* d_in, const int* in_sizes, int n_in,
                              void* d_out, int out_size, void* d_ws,
                              size_t ws_size, hipStream_t stream) {
  const float* x = (const float*)d_in[0];       // (4, 8192, 1024) f32
  const float* matrix = (const float*)d_in[1];  // (64, 64) f32
  const float* thetas = (const float*)d_in[2];  // (32,) f32
  const float* tscale = (const float*)d_in[3];  // (1,) f32
  const float* invf = (const float*)d_in[4];    // (32,) f32
  const int* pairs = (const int*)d_in[5];       // (32, 2) i32
  float* out = (float*)d_out;

  float* M = (float*)d_ws;   // 4096 f
  float* tab = M + DD * DD;  // SS*64 f = 2 MB
  const size_t need = (size_t)(DD * DD + SS * 64) * sizeof(float);
  const bool have_tab = ws_size >= need;

  setup_GM<<<16, 256, 0, stream>>>(thetas, tscale, pairs, matrix, M);
  if (have_tab) setup_table<<<(SS * 32) / 256, 256, 0, stream>>>(invf, tab);
  apply_rot<<<NBLK, TPB, 0, stream>>>(x, M, have_tab ? tab : nullptr, invf,
                                      out);
}

// Round 5
// 302.018 us; speedup vs baseline: 1.0621x; 1.0621x over previous
//
#include <hip/hip_runtime.h>
#include <math.h>

#define BB 4
#define SS 8192
#define HH 16
#define DD 64
#define ROT 32
#define NG (BB * SS * HH)  // 524288 token-head rows
#define RPB 128            // rows per tile
#define LSTR 65            // LDS row stride in floats (pad +1 -> rotated banks)
#define TPB 512            // threads per block (8 waves)
#define NBLK 512           // persistent blocks: 2 per CU
#define TILES (NG / (RPB * NBLK))  // 8 tiles per block

typedef float f32x4 __attribute__((ext_vector_type(4)));  // native vec for NT store

// lgkm-only barrier: LDS visibility without draining global loads/stores.
// __syncthreads() emits s_waitcnt vmcnt(0) before s_barrier, which forces the
// prefetch loads AND the NT store queue to retire every phase (the R3 stall).
#define BAR() asm volatile("s_waitcnt lgkmcnt(0)\n\ts_barrier" ::: "memory")

// ---------------------------------------------------------------------------
// Merged setup: G_comb = I @ G_0 @ ... @ G_31 built in LDS (threads 0..63,
// column-op per row, no syncs needed among them), then M = G @ matrix.
// i==j edge: .at chain leaves G[i,i]=sin -> column i scaled by sin.
// ---------------------------------------------------------------------------
__global__ void setup_GM(const float* __restrict__ thetas,
                         const float* __restrict__ tscale,
                         const int* __restrict__ pairs,
                         const float* __restrict__ matrix,
                         float* __restrict__ M) {
  __shared__ float Gs[DD][DD];
  const int t = threadIdx.x;
  if (t < DD) {
    for (int c = 0; c < DD; ++c) Gs[t][c] = (t == c) ? 1.0f : 0.0f;
    const float ts = tscale[0];
    for (int r = 0; r < ROT; ++r) {
      const int i = pairs[2 * r], j = pairs[2 * r + 1];
      const float th = thetas[r] * ts;
      const float cc = cosf(th), sn = sinf(th);
      if (i == j) {
        Gs[t][i] *= sn;
      } else {
        const float a = Gs[t][i], b = Gs[t][j];
        Gs[t][i] = a * cc + b * sn;
        Gs[t][j] = b * cc - a * sn;
      }
    }
  }
  __syncthreads();
  const int e = blockIdx.x * 256 + t;
  const int row = e >> 6, col = e & 63;  // row wave-uniform -> LDS broadcast
  float a0 = 0.f, a1 = 0.f, a2 = 0.f, a3 = 0.f;
  for (int k = 0; k < DD; k += 4) {
    a0 = fmaf(Gs[row][k], matrix[k * DD + col], a0);
    a1 = fmaf(Gs[row][k + 1], matrix[(k + 1) * DD + col], a1);
    a2 = fmaf(Gs[row][k + 2], matrix[(k + 2) * DD + col], a2);
    a3 = fmaf(Gs[row][k + 3], matrix[(k + 3) * DD + col], a3);
  }
  M[e] = (a0 + a1) + (a2 + a3);
}

// cos/sin table PRESCALED by 32 (the sqrt(dims) factor fused here).
// tab[s*64 + d] = 32*cos(s*invf[d]); tab[s*64 + 32 + d] = 32*sin(...)
__global__ void setup_table(const float* __restrict__ invf,
                            float* __restrict__ tab) {
  const int idx = blockIdx.x * 256 + threadIdx.x;
  if (idx >= SS * 32) return;
  const int s = idx >> 5, d = idx & 31;
  const float ang = (float)s * invf[d];
  tab[s * 64 + d] = 32.0f * cosf(ang);
  tab[s * 64 + 32 + d] = 32.0f * sinf(ang);
}

// ---------------------------------------------------------------------------
// Main kernel: double-buffered LDS (2 blocks/CU), cross-tile register
// prefetch, lgkm-only barriers (2 per tile), NT stores never drained.
// Per tile t (steady state):
//   B: compute from lds[p]   (x(t+1) loads are in flight, issued last iter)
//   BAR1  (lgkm)             -> all lds[p] reads retired
//   C: outputs -> lds[p]; staged x(t+1) -> lds[p^1]
//      (the ds_write of st waits vmcnt for the loads only: they are OLDER
//       in the vmem queue than any unretired store)
//   BAR2  (lgkm)             -> both buffers consistent
//   A: issue x(t+2) loads -> st   (before D so loads precede stores in queue)
//   D: ds_read lds[p] -> NT global store (fire and forget)
// ---------------------------------------------------------------------------
__global__ __launch_bounds__(TPB, 4) void apply_rot(
    const float* __restrict__ x, const float* __restrict__ M,
    const float* __restrict__ tab, const float* __restrict__ invf,
    float* __restrict__ out) {
  __shared__ float lds[2][RPB * LSTR];  // 2 x 33280 B
  const int tid = threadIdx.x;
  const int r = tid & (RPB - 1);
  const int h = __builtin_amdgcn_readfirstlane(tid >> 7);  // 0..3, wave-uniform
  const float* __restrict__ Mh = M + h * 16;
  const size_t tile0 = (size_t)blockIdx.x * TILES;

  // Per-thread LDS float-offsets for the stage/store f-map.
  int fa[4];
#pragma unroll
  for (int i = 0; i < 4; ++i) {
    const int f = i * TPB + tid;
    fa[i] = (f >> 4) * LSTR + (f & 15) * 4;
  }

  // Prologue: stage x(tile0) -> lds[0]; issue x(tile0+1) -> st; lgkm barrier
  // (x(+1) loads stay in flight across it).
  float4 st0, st1, st2, st3;
  {
    const float4* __restrict__ xg = (const float4*)x + tile0 * (RPB * 16);
    const float4 s0 = xg[0 * TPB + tid], s1 = xg[1 * TPB + tid],
                 s2 = xg[2 * TPB + tid], s3 = xg[3 * TPB + tid];
    *(float4*)&lds[0][fa[0]] = s0;
    *(float4*)&lds[0][fa[1]] = s1;
    *(float4*)&lds[0][fa[2]] = s2;
    *(float4*)&lds[0][fa[3]] = s3;
    const float4* __restrict__ xn =
        (const float4*)x + (tile0 + 1) * (RPB * 16);
    st0 = xn[0 * TPB + tid];
    st1 = xn[1 * TPB + tid];
    st2 = xn[2 * TPB + tid];
    st3 = xn[3 * TPB + tid];
  }
  BAR();

  int p = 0;
#pragma unroll 1
  for (int t = 0; t < TILES; ++t) {
    const size_t tile = tile0 + t;
    const int g = (int)(tile * RPB) + r;
    const int spos = (g >> 4) & (SS - 1);

    // tab loads for THIS tile (small, L2/L3-hot).
    float cz[8], sz[8];
    if (tab) {
      const float4* __restrict__ tc = (const float4*)(tab + spos * 64 + h * 8);
      const float4* __restrict__ tn =
          (const float4*)(tab + spos * 64 + 32 + h * 8);
      *(float4*)&cz[0] = tc[0];
      *(float4*)&cz[4] = tc[1];
      *(float4*)&sz[0] = tn[0];
      *(float4*)&sz[4] = tn[1];
    }

    // B: thread (r,h) computes cols [16h, 16h+16) of row r.
    const float* __restrict__ xr = &lds[p][r * LSTR];
    float acc[16];
#pragma unroll
    for (int c = 0; c < 16; ++c) acc[c] = 0.0f;

#pragma unroll 4
    for (int k4 = 0; k4 < 16; ++k4) {
      const float4 xv = *(const float4*)&xr[k4 * 4];
      const float* __restrict__ m0 = Mh + k4 * 4 * DD;  // uniform -> s_load
#pragma unroll
      for (int c = 0; c < 16; ++c) acc[c] = fmaf(xv.x, m0[c], acc[c]);
#pragma unroll
      for (int c = 0; c < 16; ++c) acc[c] = fmaf(xv.y, m0[DD + c], acc[c]);
#pragma unroll
      for (int c = 0; c < 16; ++c) acc[c] = fmaf(xv.z, m0[2 * DD + c], acc[c]);
#pragma unroll
      for (int c = 0; c < 16; ++c) acc[c] = fmaf(xv.w, m0[3 * DD + c], acc[c]);
    }

    if (!tab) {
#pragma unroll
      for (int d = 0; d < 8; ++d) {
        const float ang = (float)spos * invf[h * 8 + d];
        cz[d] = 32.0f * cosf(ang);
        sz[d] = 32.0f * sinf(ang);
      }
    }

    // RoPE epilogue: pairs (2d,2d+1) -> out cols d (lo) and 32+d (hi), d=8h+d'.
    float4 lov[2], hiv[2];
#pragma unroll
    for (int q = 0; q < 2; ++q) {
#pragma unroll
      for (int d = 0; d < 4; ++d) {
        const int dd = 4 * q + d;
        const float e = acc[2 * dd], o = acc[2 * dd + 1];
        ((float*)&lov[q])[d] = e * cz[dd] - o * sz[dd];
        ((float*)&hiv[q])[d] = e * sz[dd] + o * cz[dd];
      }
    }

    // BAR1: all lds[p] x-reads (and last iter's store-phase reads) retired.
    BAR();

    // C: outputs -> lds[p]; staged next x -> lds[p^1].
    float* __restrict__ orow = &lds[p][r * LSTR];
    *(float4*)&orow[8 * h + 0] = lov[0];
    *(float4*)&orow[8 * h + 4] = lov[1];
    *(float4*)&orow[32 + 8 * h + 0] = hiv[0];
    *(float4*)&orow[32 + 8 * h + 4] = hiv[1];
    if (t + 1 < TILES) {
      float* __restrict__ nb = lds[p ^ 1];
      *(float4*)&nb[fa[0]] = st0;  // vmcnt wait here covers loads only
      *(float4*)&nb[fa[1]] = st1;
      *(float4*)&nb[fa[2]] = st2;
      *(float4*)&nb[fa[3]] = st3;
    }

    // BAR2: output tile assembled; staged buffer ready for next iteration.
    BAR();

    // A: issue x(t+2) loads now, BEFORE the stores, so the loads sit ahead
    // of the stores in the vmcnt queue (C's wait never drains stores).
    if (t + 2 < TILES) {
      const float4* __restrict__ xn =
          (const float4*)x + (tile + 2) * (RPB * 16);
      st0 = xn[0 * TPB + tid];
      st1 = xn[1 * TPB + tid];
      st2 = xn[2 * TPB + tid];
      st3 = xn[3 * TPB + tid];
    }

    // D: coalesced NT stores from lds[p] (never waited on inside the loop).
    float4* __restrict__ og = (float4*)out + tile * (RPB * 16);
#pragma unroll
    for (int i = 0; i < 4; ++i) {
      const float4 v = *(const float4*)&lds[p][fa[i]];
      __builtin_nontemporal_store(*(const f32x4*)&v,
                                  (f32x4*)&og[i * TPB + tid]);
    }
    p ^= 1;
  }
}

// ---------------------------------------------------------------------------
extern "C" void kernel_launch(void* const* d_in, const int* in_sizes, int n_in,
                              void* d_out, int out_size, void* d_ws,
                              size_t ws_size, hipStream_t stream) {
  const float* x = (const float*)d_in[0];       // (4, 8192, 1024) f32
  const float* matrix = (const float*)d_in[1];  // (64, 64) f32
  const float* thetas = (const float*)d_in[2];  // (32,) f32
  const float* tscale = (const float*)d_in[3];  // (1,) f32
  const float* invf = (const float*)d_in[4];    // (32,) f32
  const int* pairs = (const int*)d_in[5];       // (32, 2) i32
  float* out = (float*)d_out;

  float* M = (float*)d_ws;   // 4096 f
  float* tab = M + DD * DD;  // SS*64 f = 2 MB
  const size_t need = (size_t)(DD * DD + SS * 64) * sizeof(float);
  const bool have_tab = ws_size >= need;

  setup_GM<<<16, 256, 0, stream>>>(thetas, tscale, pairs, matrix, M);
  if (have_tab) setup_table<<<(SS * 32) / 256, 256, 0, stream>>>(invf, tab);
  apply_rot<<<NBLK, TPB, 0, stream>>>(x, M, have_tab ? tab : nullptr, invf,
                                      out);
}

// Round 6
// 279.102 us; speedup vs baseline: 1.1493x; 1.0821x over previous
//
#include <hip/hip_runtime.h>
#include <math.h>

#define BB 4
#define SS 8192
#define HH 16
#define DD 64
#define ROT 32
#define NG (BB * SS * HH)  // 524288 token-head rows
#define RPB 64             // rows per block (half of R0 -> 8 blocks/CU)
#define LSTR 65            // LDS row stride in floats (pad +1 -> rotated banks)
#define TPB 256            // threads per block (4 waves)

typedef float f32x4 __attribute__((ext_vector_type(4)));  // native vec for NT store

// ---------------------------------------------------------------------------
// Merged setup: G_comb = I @ G_0 @ ... @ G_31 built in LDS (threads 0..63,
// column-op per row, no syncs needed among them), then M = G @ matrix.
// i==j edge: .at chain leaves G[i,i]=sin -> column i scaled by sin.
// ---------------------------------------------------------------------------
__global__ void setup_GM(const float* __restrict__ thetas,
                         const float* __restrict__ tscale,
                         const int* __restrict__ pairs,
                         const float* __restrict__ matrix,
                         float* __restrict__ M) {
  __shared__ float Gs[DD][DD];
  const int t = threadIdx.x;
  if (t < DD) {
    for (int c = 0; c < DD; ++c) Gs[t][c] = (t == c) ? 1.0f : 0.0f;
    const float ts = tscale[0];
    for (int r = 0; r < ROT; ++r) {
      const int i = pairs[2 * r], j = pairs[2 * r + 1];
      const float th = thetas[r] * ts;
      const float cc = cosf(th), sn = sinf(th);
      if (i == j) {
        Gs[t][i] *= sn;
      } else {
        const float a = Gs[t][i], b = Gs[t][j];
        Gs[t][i] = a * cc + b * sn;
        Gs[t][j] = b * cc - a * sn;
      }
    }
  }
  __syncthreads();
  const int e = blockIdx.x * 256 + t;
  const int row = e >> 6, col = e & 63;  // row wave-uniform -> LDS broadcast
  float a0 = 0.f, a1 = 0.f, a2 = 0.f, a3 = 0.f;
  for (int k = 0; k < DD; k += 4) {
    a0 = fmaf(Gs[row][k], matrix[k * DD + col], a0);
    a1 = fmaf(Gs[row][k + 1], matrix[(k + 1) * DD + col], a1);
    a2 = fmaf(Gs[row][k + 2], matrix[(k + 2) * DD + col], a2);
    a3 = fmaf(Gs[row][k + 3], matrix[(k + 3) * DD + col], a3);
  }
  M[e] = (a0 + a1) + (a2 + a3);
}

// cos/sin table PRESCALED by 32 (the sqrt(dims) factor fused here).
// tab[s*64 + d] = 32*cos(s*invf[d]); tab[s*64 + 32 + d] = 32*sin(...)
__global__ void setup_table(const float* __restrict__ invf,
                            float* __restrict__ tab) {
  const int idx = blockIdx.x * 256 + threadIdx.x;
  if (idx >= SS * 32) return;
  const int s = idx >> 5, d = idx & 31;
  const float ang = (float)s * invf[d];
  tab[s * 64 + d] = 32.0f * cosf(ang);
  tab[s * 64 + 32 + d] = 32.0f * sinf(ang);
}

// ---------------------------------------------------------------------------
// Main kernel, R0 structure with HALF the tile: 64 rows / 256 threads /
// 16.6 KB LDS -> 8 independent blocks per CU (vs 4 in R0, 2 in R3/R5).
// Theory: the kernel is memory-dominated at the EFFECTIVE BW its burst/gap
// pattern achieves (~2-2.6 TB/s). Every round so far had 2-4 barrier-synced
// convoys per CU alternating HBM-burst / VALU-burst. 8 staggered independent
// blocks keep the memory pipe near-continuously fed and cover each other's
// compute-phase s_load stalls. Inner loop unchanged (proven since R0).
// ---------------------------------------------------------------------------
__global__ __launch_bounds__(TPB, 8) void apply_rot(
    const float* __restrict__ x, const float* __restrict__ M,
    const float* __restrict__ tab, const float* __restrict__ invf,
    float* __restrict__ out) {
  __shared__ float lds[RPB * LSTR];  // 16640 B -> 8 blocks/CU (wave-capped)
  const int tid = threadIdx.x;
  const size_t R0 = (size_t)blockIdx.x * RPB;

  // Phase 1: coalesced float4 loads of 64 rows -> padded LDS tile.
  const float4* __restrict__ xg = (const float4*)x + R0 * 16;
#pragma unroll
  for (int i = 0; i < 4; ++i) {
    const int f = i * TPB + tid;  // float4 index in tile [0,1024)
    const int row = f >> 4, c4 = f & 15;
    const float4 v = xg[f];
    *(float4*)&lds[row * LSTR + c4 * 4] = v;
  }
  __syncthreads();

  // Phase 2: thread (r,h) computes cols [16h, 16h+16) of row r.
  const int r = tid & (RPB - 1);
  const int h = __builtin_amdgcn_readfirstlane(tid >> 6);  // 0..3, wave-uniform
  const float* __restrict__ Mh = M + h * 16;
  const float* __restrict__ xr = &lds[r * LSTR];

  float acc[16];
#pragma unroll
  for (int c = 0; c < 16; ++c) acc[c] = 0.0f;

#pragma unroll 4
  for (int k4 = 0; k4 < 16; ++k4) {
    const float4 xv = *(const float4*)&xr[k4 * 4];
    const float* __restrict__ m0 = Mh + k4 * 4 * DD;  // uniform -> s_load
#pragma unroll
    for (int c = 0; c < 16; ++c) acc[c] = fmaf(xv.x, m0[c], acc[c]);
#pragma unroll
    for (int c = 0; c < 16; ++c) acc[c] = fmaf(xv.y, m0[DD + c], acc[c]);
#pragma unroll
    for (int c = 0; c < 16; ++c) acc[c] = fmaf(xv.z, m0[2 * DD + c], acc[c]);
#pragma unroll
    for (int c = 0; c < 16; ++c) acc[c] = fmaf(xv.w, m0[3 * DD + c], acc[c]);
  }

  // Epilogue (tab loads HERE so cz/sz don't inflate the loop's live set).
  const int g = (int)R0 + r;
  const int spos = (g >> 4) & (SS - 1);
  float cz[8], sz[8];
  if (tab) {
    const float4* __restrict__ tc = (const float4*)(tab + spos * 64 + h * 8);
    const float4* __restrict__ tn =
        (const float4*)(tab + spos * 64 + 32 + h * 8);
    *(float4*)&cz[0] = tc[0];
    *(float4*)&cz[4] = tc[1];
    *(float4*)&sz[0] = tn[0];
    *(float4*)&sz[4] = tn[1];
  } else {
#pragma unroll
    for (int d = 0; d < 8; ++d) {
      const float ang = (float)spos * invf[h * 8 + d];
      cz[d] = 32.0f * cosf(ang);
      sz[d] = 32.0f * sinf(ang);
    }
  }

  // RoPE pairs (2d,2d+1) -> out cols d (lo) and 32+d (hi), d=8h+d'.
  float4 lov[2], hiv[2];
#pragma unroll
  for (int q = 0; q < 2; ++q) {
#pragma unroll
    for (int d = 0; d < 4; ++d) {
      const int dd = 4 * q + d;
      const float e = acc[2 * dd], o = acc[2 * dd + 1];
      ((float*)&lov[q])[d] = e * cz[dd] - o * sz[dd];
      ((float*)&hiv[q])[d] = e * sz[dd] + o * cz[dd];
    }
  }

  __syncthreads();  // all LDS x-reads complete before overwrite
  float* __restrict__ orow = &lds[r * LSTR];
  *(float4*)&orow[8 * h + 0] = lov[0];
  *(float4*)&orow[8 * h + 4] = lov[1];
  *(float4*)&orow[32 + 8 * h + 0] = hiv[0];
  *(float4*)&orow[32 + 8 * h + 4] = hiv[1];
  __syncthreads();

  // Phase 3: coalesced NT float4 stores from LDS.
  float4* __restrict__ og = (float4*)out + R0 * 16;
#pragma unroll
  for (int i = 0; i < 4; ++i) {
    const int f = i * TPB + tid;
    const float4 v = *(const float4*)&lds[(f >> 4) * LSTR + (f & 15) * 4];
    __builtin_nontemporal_store(*(const f32x4*)&v, (f32x4*)&og[f]);
  }
}

// ---------------------------------------------------------------------------
extern "C" void kernel_launch(void* const* d_in, const int* in_sizes, int n_in,
                              void* d_out, int out_size, void* d_ws,
                              size_t ws_size, hipStream_t stream) {
  const float* x = (const float*)d_in[0];       // (4, 8192, 1024) f32
  const float* matrix = (const float*)d_in[1];  // (64, 64) f32
  const float* thetas = (const float*)d_in[2];  // (32,) f32
  const float* tscale = (const float*)d_in[3];  // (1,) f32
  const float* invf = (const float*)d_in[4];    // (32,) f32
  const int* pairs = (const int*)d_in[5];       // (32, 2) i32
  float* out = (float*)d_out;

  float* M = (float*)d_ws;   // 4096 f
  float* tab = M + DD * DD;  // SS*64 f = 2 MB
  const size_t need = (size_t)(DD * DD + SS * 64) * sizeof(float);
  const bool have_tab = ws_size >= need;

  setup_GM<<<16, 256, 0, stream>>>(thetas, tscale, pairs, matrix, M);
  if (have_tab) setup_table<<<(SS * 32) / 256, 256, 0, stream>>>(invf, tab);
  apply_rot<<<NG / RPB, TPB, 0, stream>>>(x, M, have_tab ? tab : nullptr, invf,
                                          out);
}